// Round 2
// baseline (91.464 us; speedup 1.0000x reference)
//
#include <hip/hip_runtime.h>

#define NKC 256   // clusters (K)
#define ND  64    // feature dim (D)

using v8bf = __attribute__((ext_vector_type(8))) __bf16;
using v4f  = __attribute__((ext_vector_type(4))) float;
using v4u  = __attribute__((ext_vector_type(4))) unsigned int;

__device__ __forceinline__ unsigned short f2bf(float f) {
    // round-to-nearest-even f32 -> bf16 (inputs are finite normals; no NaN path)
    unsigned int x = __float_as_uint(f);
    x += 0x7FFFu + ((x >> 16) & 1u);
    return (unsigned short)(x >> 16);
}

// Convert clusters (256x64 f32) to bf16 + per-row sum of squares, into workspace.
__global__ void prep_kernel(const float* __restrict__ clusters,
                            unsigned short* __restrict__ cbf,
                            float* __restrict__ csq) {
    int t = threadIdx.x;
    int lane = t & 63;
    int row = blockIdx.x * 4 + (t >> 6);
    float v = clusters[row * ND + lane];
    cbf[row * ND + lane] = f2bf(v);
    float p = v * v;
#pragma unroll
    for (int m = 1; m <= 32; m <<= 1) p += __shfl_xor(p, m);
    if (lane == 0) csq[row] = p;
}

// LDS-free, barrier-free: each wave owns 16 x-rows x all 256 clusters.
// B fragments (32KB bf16) live in 128 VGPRs, loaded once per block (persistent
// grid-stride loop amortizes). x rows stream global->reg->bf16. No __shared__.
__global__ __launch_bounds__(256, 2)
void cluster_kernel(const float* __restrict__ x,
                    const unsigned short* __restrict__ cbf,
                    const float* __restrict__ csq,
                    float* __restrict__ out,
                    int ntiles) {
    const int t    = threadIdx.x;
    const int lane = t & 63;
    const int wid  = t >> 6;        // wave in block (0..3)
    const int lr   = lane & 15;
    const int hi   = lane >> 4;     // 0..3
    const int kg   = hi << 3;       // k-offset within 32: 0,8,16,24

    // ---- B fragments: cluster row (j*16+lr), k = half*32 + kg + {0..7}
    v8bf b[16][2];
#pragma unroll
    for (int j = 0; j < 16; ++j) {
        const unsigned short* bp = cbf + (j * 16 + lr) * ND + kg;
        b[j][0] = *(const v8bf*)(bp);
        b[j][1] = *(const v8bf*)(bp + 32);
    }

    for (int tile = blockIdx.x; tile < ntiles; tile += gridDim.x) {
        const int row0 = tile * 64 + wid * 16;      // wave's first row
        // ---- A: lane loads row (row0+lr), k = kg+{0..7} and 32+kg+{0..7}
        const float* xp = x + (size_t)(row0 + lr) * ND + kg;
        v4f x00 = *(const v4f*)(xp);
        v4f x01 = *(const v4f*)(xp + 4);
        v4f x10 = *(const v4f*)(xp + 32);
        v4f x11 = *(const v4f*)(xp + 36);

        float v0[8], v1[8];
        *(v4f*)&v0[0] = x00; *(v4f*)&v0[4] = x01;
        *(v4f*)&v1[0] = x10; *(v4f*)&v1[4] = x11;

        // partial sum of squares of this lane's 16 elems of row (row0+lr)
        float p = 0.f;
#pragma unroll
        for (int i = 0; i < 8; ++i) p += v0[i] * v0[i] + v1[i] * v1[i];
        // full row sumsq: reduce across the 4 hi-groups holding the same lr
        p += __shfl_xor(p, 16);
        p += __shfl_xor(p, 32);

        v4u u0, u1;
#pragma unroll
        for (int i = 0; i < 4; ++i) {
            u0[i] = (unsigned)f2bf(v0[2 * i]) | ((unsigned)f2bf(v0[2 * i + 1]) << 16);
            u1[i] = (unsigned)f2bf(v1[2 * i]) | ((unsigned)f2bf(v1[2 * i + 1]) << 16);
        }
        v8bf a0 = *(v8bf*)&u0;
        v8bf a1 = *(v8bf*)&u1;

        // ---- MFMA: 16 col-tiles x (K=64 as 2 steps)
        v4f acc[16];
#pragma unroll
        for (int j = 0; j < 16; ++j) {
            v4f c = {0.f, 0.f, 0.f, 0.f};
            c = __builtin_amdgcn_mfma_f32_16x16x32_bf16(a0, b[j][0], c, 0, 0, 0);
            c = __builtin_amdgcn_mfma_f32_16x16x32_bf16(a1, b[j][1], c, 0, 0, 0);
            acc[j] = c;
        }

        // ---- epilogue. C/D layout: col = lane&15 (cluster j*16+lr),
        // row = (lane>>4)*4 + reg  -> global row = row0 + hi*4 + r
        float xs[4];
#pragma unroll
        for (int r = 0; r < 4; ++r) xs[r] = __shfl(p, (hi << 2) + r);

        float ps[4] = {0.f, 0.f, 0.f, 0.f};
#pragma unroll
        for (int j = 0; j < 16; ++j) {
            const float cs = csq[(j << 4) + lr];   // L1-hot after first tile
#pragma unroll
            for (int r = 0; r < 4; ++r) {
                float d = xs[r] + cs - 2.0f * acc[j][r];
                float u = __builtin_amdgcn_rcpf(1.0f + d);
                acc[j][r] = u;
                ps[r] += u;
            }
        }
#pragma unroll
        for (int m = 1; m <= 8; m <<= 1) {
#pragma unroll
            for (int r = 0; r < 4; ++r) ps[r] += __shfl_xor(ps[r], m);
        }
        float inv[4];
#pragma unroll
        for (int r = 0; r < 4; ++r) inv[r] = __builtin_amdgcn_rcpf(ps[r]);

        float* orow = out + (size_t)(row0 + (hi << 2)) * NKC + lr;
#pragma unroll
        for (int r = 0; r < 4; ++r) {
#pragma unroll
            for (int j = 0; j < 16; ++j) {
                orow[(size_t)r * NKC + (j << 4)] = acc[j][r] * inv[r];
            }
        }
    }
}

extern "C" void kernel_launch(void* const* d_in, const int* in_sizes, int n_in,
                              void* d_out, int out_size, void* d_ws, size_t ws_size,
                              hipStream_t stream) {
    const float* x        = (const float*)d_in[0];
    const float* clusters = (const float*)d_in[1];
    float* out = (float*)d_out;
    const int N = in_sizes[0] / ND;                 // 262144
    const int ntiles = N / 64;                      // 4096

    unsigned short* cbf = (unsigned short*)d_ws;                         // 32 KB
    float* csq = (float*)((char*)d_ws + (size_t)NKC * ND * sizeof(unsigned short));

    prep_kernel<<<NKC / 4, 256, 0, stream>>>(clusters, cbf, csq);
    cluster_kernel<<<512, 256, 0, stream>>>(x, cbf, csq, out, ntiles);
}